// Round 9
// baseline (181.085 us; speedup 1.0000x reference)
//
#include <hip/hip_runtime.h>
#include <stdint.h>

// GradientLoss: sum_c mean( (conv3d_c(x) - conv3d_c(y))^2 ), c in {d,h,w} Sobel dirs.
// conv linear -> conv(x)-conv(y) = conv(x-y). Separable: s=[1,2,1], g=[1,0,-1];
// SAME zero pad; squared output -> flip irrelevant.
//
// R8: wave-private streaming, ZERO barriers. R7 (45us) still convoyed 4 waves
// per block at each vmcnt(5)+s_barrier, prefetch distance 2 (~500cyc) < HBM
// latency (~900cyc), and 960 blocks / 512 resident = 1.875 rounds (tail).
// Now: block = ONE wave staging exactly the 4 rows x {x,y} it reads ->
// no cross-wave dependency -> no s_barrier anywhere in the loop. Private
// 32 KB LDS, 4 buffers, prefetch distance 3 (~1500 cyc cover). Every iter
// issues exactly 8 DMAs (clamped addresses at h/d edges, masked on read),
// so "s_waitcnt vmcnt(16)" = oldest plane landed, 2 planes in flight.
// 5 blocks/CU (LDS 32KB of 160KB); grid 3840 = 3 exact rounds of 1280.

#define N_  2
#define D_  160
#define H_  192
#define W_  224
#define PS  (H_ * W_)

#define TD   8                  // d-planes computed per block
#define NBUF 4                  // LDS plane buffers (prefetch distance 3)
constexpr int RPAD = 256;       // floats per row slot (64 lanes x 16B = 1KB)
constexpr float SCALE = 1.0f / ((float)N_ * D_ * H_ * W_);

#define DMA16(gp, lp) __builtin_amdgcn_global_load_lds(                        \
    (const __attribute__((address_space(1))) void*)(gp),                       \
    (__attribute__((address_space(3))) void*)(lp), 16, 0, 0)

__global__ __launch_bounds__(64, 1)
void grad_loss_kernel(const float* __restrict__ x, const float* __restrict__ y,
                      float* __restrict__ out) {
    __shared__ float sbuf[NBUF][4][2][RPAD];   // 4 bufs x 4 rows x {x,y} x 1KB

    const int lane = threadIdx.x;              // block = one wave

    const int h0 = blockIdx.y * 2;             // this wave's 2 output rows
    const int nchunks = D_ / TD;               // 20
    const int nb = blockIdx.z / nchunks;
    const int d0 = (blockIdx.z % nchunks) * TD;

    const float* vbx = x + (size_t)nb * ((size_t)D_ * PS);
    const float* vby = y + (size_t)nb * ((size_t)D_ * PS);

    // per-lane source float offset in a row; lanes 56..63 duplicate lane 55
    // (their LDS bytes land in the row pad [896,1024) and are read only as
    // masked-to-zero values)
    const int lo = (lane < 56 ? lane : 55) * 4;

    // ---- 8 staging items: (row k 0..3) x (array a 0..1), clamped h ----
    const float* sp[8];
    #pragma unroll
    for (int k = 0; k < 4; ++k) {
        int ghc = min(max(h0 - 1 + k, 0), H_ - 1);   // clamp; zeroed via rmask
        sp[2 * k + 0] = vbx + ghc * W_ + lo;
        sp[2 * k + 1] = vby + ghc * W_ + lo;
    }

    auto stage = [&](int p, int bsel) {
        int pc = min(max(p, 0), D_ - 1);             // clamp; zeroed via pm
        size_t poff = (size_t)pc * PS;
        #pragma unroll
        for (int i = 0; i < 8; ++i)
            DMA16(sp[i] + poff, &sbuf[bsel][i >> 1][i & 1][0]);
    };

    // ---- compute-side masks ----
    const bool wact = lane < 56;                     // 56 x 4 = 224 = W
    float rmask[4];
    #pragma unroll
    for (int r = 0; r < 4; ++r)
        rmask[r] = (((unsigned)(h0 - 1 + r) < (unsigned)H_) && wact) ? 1.f : 0.f;
    const int lrd = lane * 4;

    float4 A0[2], A1[2], A2[2], B0[2], B1[2], B2[2]; // d-history (p-2, p-1)
    const float4 z4 = make_float4(0.f, 0.f, 0.f, 0.f);
    #pragma unroll
    for (int j = 0; j < 2; ++j) { A0[j]=A1[j]=A2[j]=B0[j]=B1[j]=B2[j]=z4; }
    float acc = 0.f;

    // ---- prologue: planes d0-1, d0, d0+1 -> bufs 0,1,2 (24 DMAs) ----
    stage(d0 - 1, 0);
    stage(d0,     1);
    stage(d0 + 1, 2);

    #pragma unroll
    for (int it = 0; it < TD + 2; ++it) {
        // oldest 8 outstanding = plane d0-1+it; wait for it, keep 16 in flight.
        asm volatile("s_waitcnt vmcnt(16)" ::: "memory");

        // uniform staging every iter (exact vmcnt math); late stages write
        // buffers that are never read again -> harmless.
        stage(d0 + 2 + it, (it + 3) % NBUF);

        const int q = d0 - 1 + it;                   // plane processed now
        const float pm = (q >= 0 && q < D_) ? 1.f : 0.f;
        const int bsel = it % NBUF;

        // ---- in-plane stencils from private LDS (float4 + 2 shuffles/row) ----
        float4 sw[4], gw[4];
        #pragma unroll
        for (int r = 0; r < 4; ++r) {
            const float4 xr = *(const float4*)&sbuf[bsel][r][0][lrd];
            const float4 yr = *(const float4*)&sbuf[bsel][r][1][lrd];
            const float m = rmask[r] * pm;
            float4 v = make_float4((xr.x - yr.x) * m, (xr.y - yr.y) * m,
                                   (xr.z - yr.z) * m, (xr.w - yr.w) * m);
            float Lm = __shfl_up(v.w, 1, 64);
            float Rp = __shfl_down(v.x, 1, 64);
            if (lane == 0) Lm = 0.f;                 // w = -1 zero pad
            // lane 55's Rp comes from lane 56: v there is 0 (wact mask)
            sw[r] = make_float4(Lm + 2.f * v.x + v.y,
                                v.x + 2.f * v.y + v.z,
                                v.y + 2.f * v.z + v.w,
                                v.z + 2.f * v.w + Rp);
            gw[r] = make_float4(Lm - v.y, v.x - v.z, v.y - v.w, v.z - Rp);
        }
        float4 n0[2], n1[2], n2[2];
        #pragma unroll
        for (int j = 0; j < 2; ++j) {
            n0[j] = make_float4(sw[j].x + 2.f * sw[j+1].x + sw[j+2].x,
                                sw[j].y + 2.f * sw[j+1].y + sw[j+2].y,
                                sw[j].z + 2.f * sw[j+1].z + sw[j+2].z,
                                sw[j].w + 2.f * sw[j+1].w + sw[j+2].w);  // s_h s_w
            n1[j] = make_float4(sw[j].x - sw[j+2].x, sw[j].y - sw[j+2].y,
                                sw[j].z - sw[j+2].z, sw[j].w - sw[j+2].w); // g_h s_w
            n2[j] = make_float4(gw[j].x + 2.f * gw[j+1].x + gw[j+2].x,
                                gw[j].y + 2.f * gw[j+1].y + gw[j+2].y,
                                gw[j].z + 2.f * gw[j+1].z + gw[j+2].z,
                                gw[j].w + 2.f * gw[j+1].w + gw[j+2].w);  // s_h g_w
        }

        // ---- d-combine for center plane q-1 (A = q-2, B = q-1, n = q) ----
        if (it >= 2 && wact) {
            #pragma unroll
            for (int j = 0; j < 2; ++j) {
                float4 gx = make_float4(A0[j].x - n0[j].x, A0[j].y - n0[j].y,
                                        A0[j].z - n0[j].z, A0[j].w - n0[j].w);
                float4 gy = make_float4(A1[j].x + 2.f * B1[j].x + n1[j].x,
                                        A1[j].y + 2.f * B1[j].y + n1[j].y,
                                        A1[j].z + 2.f * B1[j].z + n1[j].z,
                                        A1[j].w + 2.f * B1[j].w + n1[j].w);
                float4 gz = make_float4(A2[j].x + 2.f * B2[j].x + n2[j].x,
                                        A2[j].y + 2.f * B2[j].y + n2[j].y,
                                        A2[j].z + 2.f * B2[j].z + n2[j].z,
                                        A2[j].w + 2.f * B2[j].w + n2[j].w);
                acc = fmaf(gx.x, gx.x, acc); acc = fmaf(gx.y, gx.y, acc);
                acc = fmaf(gx.z, gx.z, acc); acc = fmaf(gx.w, gx.w, acc);
                acc = fmaf(gy.x, gy.x, acc); acc = fmaf(gy.y, gy.y, acc);
                acc = fmaf(gy.z, gy.z, acc); acc = fmaf(gy.w, gy.w, acc);
                acc = fmaf(gz.x, gz.x, acc); acc = fmaf(gz.y, gz.y, acc);
                acc = fmaf(gz.z, gz.z, acc); acc = fmaf(gz.w, gz.w, acc);
            }
        }

        // ---- rotate history (renamed by full unroll) ----
        #pragma unroll
        for (int j = 0; j < 2; ++j) {
            A0[j] = B0[j]; A1[j] = B1[j]; A2[j] = B2[j];
            B0[j] = n0[j]; B1[j] = n1[j]; B2[j] = n2[j];
        }
    }

    asm volatile("s_waitcnt vmcnt(0)" ::: "memory");  // drain before exit

    // ---- reduction: single-wave butterfly, one atomic per block ----
    #pragma unroll
    for (int off = 32; off > 0; off >>= 1)
        acc += __shfl_xor(acc, off, 64);
    if (lane == 0) atomicAdd(out, acc * SCALE);
}

extern "C" void kernel_launch(void* const* d_in, const int* in_sizes, int n_in,
                              void* d_out, int out_size, void* d_ws, size_t ws_size,
                              hipStream_t stream) {
    const float* x = (const float*)d_in[0];
    const float* y = (const float*)d_in[1];
    float* out = (float*)d_out;

    hipMemsetAsync(out, 0, sizeof(float), stream);

    dim3 block(64);                     // one wave per block
    dim3 grid(1,
              H_ / 2,                   // 96 (2 output rows per wave)
              N_ * (D_ / TD));          // 40  -> 3840 blocks = 3 x 1280 rounds
    grad_loss_kernel<<<grid, block, 0, stream>>>(x, y, out);
}

// Round 10
// 136.300 us; speedup vs baseline: 1.3286x; 1.3286x over previous
//
#include <hip/hip_runtime.h>
#include <stdint.h>

// GradientLoss: sum_c mean( (conv3d_c(x) - conv3d_c(y))^2 ), c in {d,h,w} Sobel dirs.
// conv linear -> conv(x)-conv(y) = conv(x-y). Separable: s=[1,2,1], g=[1,0,-1];
// SAME zero pad; squared output -> flip irrelevant.
//
// R9 = R7 (best: 45us) with three coefficient fixes, same skeleton:
//  - exec-masked DMA (lanes 0..55 only) -> LDS rows pack to 896 B (=W floats),
//    LDS 60.5 -> 52.5 KB -> 3 blocks/CU (12 waves/CU) instead of 2.
//  - TD 8->16: d-halo 18/16 = 1.125x (was 1.25x); grid 480 blocks <= 768
//    resident slots -> single round, no sequential tail (R7: 1.875 rounds).
//  - stage EVERY iter with clamped plane index -> vmcnt(5) uniform, no tail
//    special case (overshoot stages write buffers never read again).
// R8 lesson kept: intra-block 4-wave sharing is the only XCD-safe dedup
// (consecutive blockIdx round-robin across XCDs; cross-block halo misses L2).

#define N_  2
#define D_  160
#define H_  192
#define W_  224
#define PS  (H_ * W_)

#define TD  16                 // d-planes computed per block
#define TH  8                  // h output rows per block (2 per wave)
constexpr int SROWS = TH + 2;  // 10 staged rows per plane
constexpr int ROWF  = 224;     // floats per packed LDS row (= W, 896 B)
constexpr float SCALE = 1.0f / ((float)N_ * D_ * H_ * W_);

#define DMA16(gp, lp) __builtin_amdgcn_global_load_lds(                        \
    (const __attribute__((address_space(1))) void*)(gp),                       \
    (__attribute__((address_space(3))) void*)(lp), 16, 0, 0)

__global__ __launch_bounds__(256, 3)
void grad_loss_kernel(const float* __restrict__ x, const float* __restrict__ y,
                      float* __restrict__ out) {
    __shared__ float sbuf[3][SROWS][2][ROWF];  // 3 bufs x 10 rows x {x,y} x 896B
    __shared__ float wsum[4];

    const int tid  = threadIdx.x;
    const int lane = tid & 63;
    const int wv   = tid >> 6;

    const int h0 = blockIdx.y * TH;
    const int nchunks = D_ / TD;               // 10
    const int nb = blockIdx.z / nchunks;
    const int d0 = (blockIdx.z % nchunks) * TD;

    const float* vbx = x + (size_t)nb * ((size_t)D_ * PS);
    const float* vby = y + (size_t)nb * ((size_t)D_ * PS);

    // ---- 5 wave-uniform staging items per wave: item = (row l, array a) ----
    // DMA dest = wave-uniform base + lane*16; issued under exec mask lane<56,
    // so each row writes exactly bytes [0,896) = 224 floats = W. ✓ packed.
    int sl[5], sa[5], srw[5];
    const float* sb[5];
    #pragma unroll
    for (int k = 0; k < 5; ++k) {
        int item = 5 * wv + k;                 // 20 items over 4 waves
        sl[k] = item >> 1;
        sa[k] = item & 1;
        int ghc = min(max(h0 - 1 + sl[k], 0), H_ - 1);  // clamp; zeroed on read
        srw[k] = ghc * W_;
        sb[k]  = sa[k] ? vby : vbx;
    }
    const int lo4 = lane * 4;                  // source float offset in row

    auto stage = [&](int p, int bsel) {
        int pc = min(max(p, 0), D_ - 1);       // clamp; zeroed via pm on read
        size_t poff = (size_t)pc * PS;
        if (lane < 56) {                       // exec-masked DMA group
            #pragma unroll
            for (int k = 0; k < 5; ++k)
                DMA16(sb[k] + poff + srw[k] + lo4, &sbuf[bsel][sl[k]][sa[k]][0]);
        }
    };

    // ---- compute-side masks ----
    const bool wact = lane < 56;               // 56 lanes x 4 = 224 = W
    float rmask[4];
    #pragma unroll
    for (int r = 0; r < 4; ++r) {              // wave reads staged rows 2wv..2wv+3
        int gh = h0 - 1 + 2 * wv + r;
        rmask[r] = (((unsigned)gh < (unsigned)H_) && wact) ? 1.f : 0.f;
    }
    const int lrd = (lane < 56 ? lane : 55) * 4;  // clamped LDS read offset

    float4 A0[2], A1[2], A2[2], B0[2], B1[2], B2[2];   // d-history (p-2, p-1)
    const float4 z4 = make_float4(0.f, 0.f, 0.f, 0.f);
    #pragma unroll
    for (int j = 0; j < 2; ++j) { A0[j]=A1[j]=A2[j]=B0[j]=B1[j]=B2[j]=z4; }
    float acc = 0.f;

    // ---- prologue: plane d0-1 -> buf0, plane d0 -> buf1 (10 DMAs/wave) ----
    stage(d0 - 1, 0);
    stage(d0,     1);

    for (int it = 0; it < TD + 2; ++it) {
        // oldest 5 outstanding = this iter's plane; keep newest 5 in flight.
        asm volatile("s_waitcnt vmcnt(5)\n\ts_barrier" ::: "memory");

        // uniform staging (exact vmcnt); overshoot iters write buffers that
        // are never read again -> harmless.
        stage(d0 + 1 + it, (it + 2) % 3);

        const int q = d0 - 1 + it;             // plane processed this iter
        const float pm = (q >= 0 && q < D_) ? 1.f : 0.f;
        const int bsel = it % 3;

        // ---- in-plane stencils from LDS (float4 + 2 shuffles per row) ----
        float4 sw[4], gw[4];
        #pragma unroll
        for (int r = 0; r < 4; ++r) {
            const int l = 2 * wv + r;
            const float4 xr = *(const float4*)&sbuf[bsel][l][0][lrd];
            const float4 yr = *(const float4*)&sbuf[bsel][l][1][lrd];
            const float m = rmask[r] * pm;
            float4 v = make_float4((xr.x - yr.x) * m, (xr.y - yr.y) * m,
                                   (xr.z - yr.z) * m, (xr.w - yr.w) * m);
            float Lm = __shfl_up(v.w, 1, 64);
            float Rp = __shfl_down(v.x, 1, 64);
            if (lane == 0) Lm = 0.f;           // w = -1 zero pad
            // lane 55's Rp comes from lane 56: v there is 0 (wact mask) ✓
            sw[r] = make_float4(Lm + 2.f * v.x + v.y,
                                v.x + 2.f * v.y + v.z,
                                v.y + 2.f * v.z + v.w,
                                v.z + 2.f * v.w + Rp);
            gw[r] = make_float4(Lm - v.y, v.x - v.z, v.y - v.w, v.z - Rp);
        }
        float4 n0[2], n1[2], n2[2];
        #pragma unroll
        for (int j = 0; j < 2; ++j) {
            n0[j] = make_float4(sw[j].x + 2.f * sw[j+1].x + sw[j+2].x,
                                sw[j].y + 2.f * sw[j+1].y + sw[j+2].y,
                                sw[j].z + 2.f * sw[j+1].z + sw[j+2].z,
                                sw[j].w + 2.f * sw[j+1].w + sw[j+2].w);  // s_h s_w
            n1[j] = make_float4(sw[j].x - sw[j+2].x, sw[j].y - sw[j+2].y,
                                sw[j].z - sw[j+2].z, sw[j].w - sw[j+2].w); // g_h s_w
            n2[j] = make_float4(gw[j].x + 2.f * gw[j+1].x + gw[j+2].x,
                                gw[j].y + 2.f * gw[j+1].y + gw[j+2].y,
                                gw[j].z + 2.f * gw[j+1].z + gw[j+2].z,
                                gw[j].w + 2.f * gw[j+1].w + gw[j+2].w);  // s_h g_w
        }

        // ---- d-combine for center plane q-1 (A = q-2, B = q-1, n = q) ----
        if (it >= 2 && wact) {
            #pragma unroll
            for (int j = 0; j < 2; ++j) {
                float4 gx = make_float4(A0[j].x - n0[j].x, A0[j].y - n0[j].y,
                                        A0[j].z - n0[j].z, A0[j].w - n0[j].w);
                float4 gy = make_float4(A1[j].x + 2.f * B1[j].x + n1[j].x,
                                        A1[j].y + 2.f * B1[j].y + n1[j].y,
                                        A1[j].z + 2.f * B1[j].z + n1[j].z,
                                        A1[j].w + 2.f * B1[j].w + n1[j].w);
                float4 gz = make_float4(A2[j].x + 2.f * B2[j].x + n2[j].x,
                                        A2[j].y + 2.f * B2[j].y + n2[j].y,
                                        A2[j].z + 2.f * B2[j].z + n2[j].z,
                                        A2[j].w + 2.f * B2[j].w + n2[j].w);
                acc = fmaf(gx.x, gx.x, acc); acc = fmaf(gx.y, gx.y, acc);
                acc = fmaf(gx.z, gx.z, acc); acc = fmaf(gx.w, gx.w, acc);
                acc = fmaf(gy.x, gy.x, acc); acc = fmaf(gy.y, gy.y, acc);
                acc = fmaf(gy.z, gy.z, acc); acc = fmaf(gy.w, gy.w, acc);
                acc = fmaf(gz.x, gz.x, acc); acc = fmaf(gz.y, gz.y, acc);
                acc = fmaf(gz.z, gz.z, acc); acc = fmaf(gz.w, gz.w, acc);
            }
        }

        // ---- rotate history ----
        #pragma unroll
        for (int j = 0; j < 2; ++j) {
            A0[j] = B0[j]; A1[j] = B1[j]; A2[j] = B2[j];
            B0[j] = n0[j]; B1[j] = n1[j]; B2[j] = n2[j];
        }
    }

    asm volatile("s_waitcnt vmcnt(0)" ::: "memory");  // drain before exit

    // ---- reduction: wave butterfly, LDS combine, one atomic per block ----
    #pragma unroll
    for (int off = 32; off > 0; off >>= 1)
        acc += __shfl_xor(acc, off, 64);
    if (lane == 0) wsum[wv] = acc;
    __syncthreads();
    if (tid == 0) {
        float s = (wsum[0] + wsum[1]) + (wsum[2] + wsum[3]);
        atomicAdd(out, s * SCALE);
    }
}

extern "C" void kernel_launch(void* const* d_in, const int* in_sizes, int n_in,
                              void* d_out, int out_size, void* d_ws, size_t ws_size,
                              hipStream_t stream) {
    const float* x = (const float*)d_in[0];
    const float* y = (const float*)d_in[1];
    float* out = (float*)d_out;

    hipMemsetAsync(out, 0, sizeof(float), stream);

    dim3 block(256);                    // 4 waves; one wave = full W x 2 h-rows
    dim3 grid(1,
              H_ / TH,                  // 24
              N_ * (D_ / TD));          // 20  -> 480 blocks, 3/CU resident
    grad_loss_kernel<<<grid, block, 0, stream>>>(x, y, out);
}